// Round 3
// baseline (643.110 us; speedup 1.0000x reference)
//
#include <hip/hip_runtime.h>

// Problem: B=2, L=2048, C=1024, H=16, D=64.
// Pipeline: [k_qkv_rope] fp32 GEMM (x @ qkv_w^T) + fused RoPE + scale, scatter
//           q/k/v as bf16 [b][h][l][d] into ws.
//           [k_attn] flash attention, bf16 MFMA 16x16x32, fp32 online softmax,
//           fp32 O written as [b][l][h*64+d] into ws.
//           [k_proj] fp32 GEMM (attn @ proj_w^T) + bias -> d_out.

typedef __attribute__((ext_vector_type(8))) short s8v;   // 8 x bf16 (MFMA A/B frag)
typedef __attribute__((ext_vector_type(4))) float f4v;   // 4 x f32  (MFMA C/D frag)

__device__ __forceinline__ unsigned short f2bf(float f) {
  unsigned int u = __float_as_uint(f);
  u += 0x7FFFu + ((u >> 16) & 1u);   // RNE
  return (unsigned short)(u >> 16);
}

// ---------------------------------------------------------------------------
// GEMM1: qkv = x @ qkv_w^T  (M=4096, N=3072, K=1024), fused RoPE + q-scale,
// scatter to bf16 q/k/v in [b][h][l][d].
// 128x128x16 tiles, 256 threads, 8x8 micro-tile. LDS stored k-major with
// 8-float chunks at 12-word stride (bank-stagger, 16B-aligned b128 reads).
// ---------------------------------------------------------------------------
__global__ __launch_bounds__(256)
void k_qkv_rope(const float* __restrict__ X, const float* __restrict__ W,
                const float* __restrict__ Ct, const float* __restrict__ St,
                unsigned short* __restrict__ qb, unsigned short* __restrict__ kb,
                unsigned short* __restrict__ vb)
{
  __shared__ float As[16 * 192];
  __shared__ float Bs[16 * 192];
  const int tid = threadIdx.x;
  const int ty = tid >> 4, tx = tid & 15;
  const int row0 = blockIdx.x << 7;
  const int col0 = blockIdx.y << 7;
  const int lr = tid >> 1;            // 0..127 tile row to stage
  const int lk = (tid & 1) << 3;      // 0 or 8 (k sub-chunk)
  const int wA = (lr >> 3) * 12 + (lr & 7);

  const float* Ap = X + (size_t)(row0 + lr) * 1024 + lk;
  const float* Bp = W + (size_t)(col0 + lr) * 1024 + lk;

  float acc[8][8];
#pragma unroll
  for (int i = 0; i < 8; ++i)
#pragma unroll
    for (int j = 0; j < 8; ++j) acc[i][j] = 0.f;

  for (int k0 = 0; k0 < 1024; k0 += 16) {
    const float4 a0 = *reinterpret_cast<const float4*>(Ap + k0);
    const float4 a1 = *reinterpret_cast<const float4*>(Ap + k0 + 4);
    const float4 b0 = *reinterpret_cast<const float4*>(Bp + k0);
    const float4 b1 = *reinterpret_cast<const float4*>(Bp + k0 + 4);
    __syncthreads();
    {
      const float av[8] = {a0.x,a0.y,a0.z,a0.w,a1.x,a1.y,a1.z,a1.w};
      const float bv[8] = {b0.x,b0.y,b0.z,b0.w,b1.x,b1.y,b1.z,b1.w};
#pragma unroll
      for (int j = 0; j < 8; ++j) {
        As[(lk + j) * 192 + wA] = av[j];
        Bs[(lk + j) * 192 + wA] = bv[j];
      }
    }
    __syncthreads();
#pragma unroll
    for (int kk = 0; kk < 16; ++kk) {
      const float4 A0 = *reinterpret_cast<const float4*>(&As[kk*192 + ty*12]);
      const float4 A1 = *reinterpret_cast<const float4*>(&As[kk*192 + ty*12 + 4]);
      const float4 B0 = *reinterpret_cast<const float4*>(&Bs[kk*192 + tx*12]);
      const float4 B1 = *reinterpret_cast<const float4*>(&Bs[kk*192 + tx*12 + 4]);
      const float a[8] = {A0.x,A0.y,A0.z,A0.w,A1.x,A1.y,A1.z,A1.w};
      const float b[8] = {B0.x,B0.y,B0.z,B0.w,B1.x,B1.y,B1.z,B1.w};
#pragma unroll
      for (int i = 0; i < 8; ++i)
#pragma unroll
        for (int j = 0; j < 8; ++j)
          acc[i][j] += a[i] * b[j];
    }
  }

  // Epilogue: n = t*1024 + h*64 + d  (t uniform per block; h,d uniform per thread)
  const int t = col0 >> 10;
  const int n0 = col0 + (tx << 3);
  const int hh = (n0 & 1023) >> 6;
  const int d0 = n0 & 63;
  unsigned short* dst0 = (t == 0) ? qb : (t == 1) ? kb : vb;
  const float sc = (t == 0) ? 0.125f : 1.0f;   // logits scale folded into q

#pragma unroll
  for (int i = 0; i < 8; ++i) {
    const int m = row0 + (ty << 3) + i;
    const int bI = m >> 11;
    const int lI = m & 2047;
    s8v ov;
    if (t == 2) {
#pragma unroll
      for (int j = 0; j < 8; ++j) ov[j] = (short)f2bf(acc[i][j]);
    } else {
      const float4 c4 = *reinterpret_cast<const float4*>(Ct + lI*32 + (d0 >> 1));
      const float4 s4 = *reinterpret_cast<const float4*>(St + lI*32 + (d0 >> 1));
      const float cs[4] = {c4.x,c4.y,c4.z,c4.w};
      const float sn[4] = {s4.x,s4.y,s4.z,s4.w};
#pragma unroll
      for (int p = 0; p < 4; ++p) {
        const float e = acc[i][2*p], o = acc[i][2*p+1];
        ov[2*p]   = (short)f2bf((e*cs[p] - o*sn[p]) * sc);
        ov[2*p+1] = (short)f2bf((e*sn[p] + o*cs[p]) * sc);
      }
    }
    const size_t di = (((size_t)bI*16 + hh)*2048 + lI)*64 + d0;
    *reinterpret_cast<s8v*>(dst0 + di) = ov;
  }
}

// ---------------------------------------------------------------------------
// Flash attention: block = (b, h, 64 q-rows); 4 waves, wave w owns 16 q-rows.
// KV tile = 64. S and PV via mfma_f32_16x16x32_bf16. A/B operands use
// identical (lanegroup,elem)->k enumerations, so the HW k-permutation cancels.
// C/D layout (verified): col = lane&15, row = (lane>>4)*4 + reg.
// ---------------------------------------------------------------------------
__global__ __launch_bounds__(256)
void k_attn(const unsigned short* __restrict__ qb,
            const unsigned short* __restrict__ kb,
            const unsigned short* __restrict__ vb,
            float* __restrict__ ab)
{
  __shared__ unsigned short Ps[4][16][72];  // per-wave P tile (bf16), padded rows
  __shared__ unsigned short Vt[64][72];     // V^T tile: [d][key], padded rows

  const int tid  = threadIdx.x;
  const int w    = tid >> 6;
  const int lane = tid & 63;
  const int lr   = lane & 15;
  const int lg   = lane >> 4;

  const int bx = blockIdx.x;
  const int qt = bx & 31;
  const int h  = (bx >> 5) & 15;
  const int b  = bx >> 9;

  const size_t bh = ((size_t)b * 16 + h) * 2048;
  const unsigned short* Qp = qb + (bh + (size_t)qt*64 + w*16) * 64;
  const unsigned short* Kp = kb + bh * 64;
  const unsigned short* Vp = vb + bh * 64;

  // Q A-frags: row = lr, k-slot (lg,e) -> d = dc*32 + lg*8 + e
  const s8v qa0 = *reinterpret_cast<const s8v*>(Qp + lr*64 +  0 + lg*8);
  const s8v qa1 = *reinterpret_cast<const s8v*>(Qp + lr*64 + 32 + lg*8);

  f4v o[4];
#pragma unroll
  for (int i = 0; i < 4; ++i) o[i] = (f4v){0.f,0.f,0.f,0.f};
  float mrow[4] = {-1e30f,-1e30f,-1e30f,-1e30f};
  float lrow[4] = {0.f,0.f,0.f,0.f};

  const int vc = tid >> 2;           // key row 0..63 for V staging
  const int vd = (tid & 3) << 4;     // d base 0,16,32,48

  for (int kt = 0; kt < 32; ++kt) {
    const unsigned short* Kt = Kp + (size_t)kt * 64 * 64;
    const unsigned short* Vs = Vp + (size_t)kt * 64 * 64;

    // K B-frags direct from global: col = ct*16+lr, k-slot (lg,e) -> same d enum as Q
    s8v kf[4][2];
#pragma unroll
    for (int ct = 0; ct < 4; ++ct) {
      kf[ct][0] = *reinterpret_cast<const s8v*>(Kt + (ct*16 + lr)*64 +  0 + lg*8);
      kf[ct][1] = *reinterpret_cast<const s8v*>(Kt + (ct*16 + lr)*64 + 32 + lg*8);
    }
    const s8v v0 = *reinterpret_cast<const s8v*>(Vs + vc*64 + vd);
    const s8v v1 = *reinterpret_cast<const s8v*>(Vs + vc*64 + vd + 8);

    __syncthreads();   // previous tile's PV readers done with Vt
#pragma unroll
    for (int j = 0; j < 8; ++j) {
      Vt[vd + j][vc]     = (unsigned short)v0[j];
      Vt[vd + 8 + j][vc] = (unsigned short)v1[j];
    }

    // S = (q*scale) . K^T : rows = q-rows, cols = keys
    f4v s[4];
#pragma unroll
    for (int ct = 0; ct < 4; ++ct) {
      f4v z = (f4v){0.f,0.f,0.f,0.f};
      z = __builtin_amdgcn_mfma_f32_16x16x32_bf16(qa0, kf[ct][0], z, 0, 0, 0);
      z = __builtin_amdgcn_mfma_f32_16x16x32_bf16(qa1, kf[ct][1], z, 0, 0, 0);
      s[ct] = z;
    }

    // Online softmax; lane holds rows lg*4+r, keys ct*16+lr. Row-reduce over
    // 16-lane group (xor 1,2,4,8).
    float pexp[4][4];
#pragma unroll
    for (int r = 0; r < 4; ++r) {
      float mx = fmaxf(fmaxf(s[0][r], s[1][r]), fmaxf(s[2][r], s[3][r]));
#pragma unroll
      for (int mk = 1; mk <= 8; mk <<= 1) mx = fmaxf(mx, __shfl_xor(mx, mk));
      const float mnew = fmaxf(mrow[r], mx);
      const float corr = __expf(mrow[r] - mnew);
      mrow[r] = mnew;
      float rs = 0.f;
#pragma unroll
      for (int ct = 0; ct < 4; ++ct) {
        const float p = __expf(s[ct][r] - mnew);
        pexp[ct][r] = p;
        rs += p;
      }
#pragma unroll
      for (int mk = 1; mk <= 8; mk <<= 1) rs += __shfl_xor(rs, mk);
      lrow[r] = lrow[r] * corr + rs;
      o[0][r] *= corr; o[1][r] *= corr; o[2][r] *= corr; o[3][r] *= corr;
      const int rr = lg*4 + r;
#pragma unroll
      for (int ct = 0; ct < 4; ++ct)
        Ps[w][rr][ct*16 + lr] = f2bf(pexp[ct][r]);
    }
    __syncthreads();   // Vt fully staged (Ps is per-wave private)

    // PV: A = P (row=lr, k-slot -> key cc*32+lg*8+e), B = V^T from Vt with the
    // same key enumeration; D col = d, row = q-row.
    const s8v pa0 = *reinterpret_cast<const s8v*>(&Ps[w][lr][ 0 + lg*8]);
    const s8v pa1 = *reinterpret_cast<const s8v*>(&Ps[w][lr][32 + lg*8]);
#pragma unroll
    for (int dt = 0; dt < 4; ++dt) {
      const s8v vb0 = *reinterpret_cast<const s8v*>(&Vt[dt*16 + lr][ 0 + lg*8]);
      const s8v vb1 = *reinterpret_cast<const s8v*>(&Vt[dt*16 + lr][32 + lg*8]);
      o[dt] = __builtin_amdgcn_mfma_f32_16x16x32_bf16(pa0, vb0, o[dt], 0, 0, 0);
      o[dt] = __builtin_amdgcn_mfma_f32_16x16x32_bf16(pa1, vb1, o[dt], 0, 0, 0);
    }
  }

  // Epilogue: O /= l, write fp32 [b][l][h*64+d]
  const int lbase = qt*64 + w*16 + lg*4;
  float* obase = ab + (size_t)b * 2048 * 1024 + (size_t)h * 64;
#pragma unroll
  for (int r = 0; r < 4; ++r) {
    const float inv = 1.0f / lrow[r];
    float* orow = obase + (size_t)(lbase + r) * 1024;
    orow[ 0 + lr] = o[0][r] * inv;
    orow[16 + lr] = o[1][r] * inv;
    orow[32 + lr] = o[2][r] * inv;
    orow[48 + lr] = o[3][r] * inv;
  }
}

// ---------------------------------------------------------------------------
// GEMM2: out = attn @ proj_w^T + b  (M=4096, N=1024, K=1024), fp32.
// ---------------------------------------------------------------------------
__global__ __launch_bounds__(256)
void k_proj(const float* __restrict__ A, const float* __restrict__ W,
            const float* __restrict__ PB, float* __restrict__ OUT)
{
  __shared__ float As[16 * 192];
  __shared__ float Bs[16 * 192];
  const int tid = threadIdx.x;
  const int ty = tid >> 4, tx = tid & 15;
  const int row0 = blockIdx.x << 7;
  const int col0 = blockIdx.y << 7;
  const int lr = tid >> 1;
  const int lk = (tid & 1) << 3;
  const int wA = (lr >> 3) * 12 + (lr & 7);

  const float* Ap = A + (size_t)(row0 + lr) * 1024 + lk;
  const float* Bp = W + (size_t)(col0 + lr) * 1024 + lk;

  float acc[8][8];
#pragma unroll
  for (int i = 0; i < 8; ++i)
#pragma unroll
    for (int j = 0; j < 8; ++j) acc[i][j] = 0.f;

  for (int k0 = 0; k0 < 1024; k0 += 16) {
    const float4 a0 = *reinterpret_cast<const float4*>(Ap + k0);
    const float4 a1 = *reinterpret_cast<const float4*>(Ap + k0 + 4);
    const float4 b0 = *reinterpret_cast<const float4*>(Bp + k0);
    const float4 b1 = *reinterpret_cast<const float4*>(Bp + k0 + 4);
    __syncthreads();
    {
      const float av[8] = {a0.x,a0.y,a0.z,a0.w,a1.x,a1.y,a1.z,a1.w};
      const float bv[8] = {b0.x,b0.y,b0.z,b0.w,b1.x,b1.y,b1.z,b1.w};
#pragma unroll
      for (int j = 0; j < 8; ++j) {
        As[(lk + j) * 192 + wA] = av[j];
        Bs[(lk + j) * 192 + wA] = bv[j];
      }
    }
    __syncthreads();
#pragma unroll
    for (int kk = 0; kk < 16; ++kk) {
      const float4 A0 = *reinterpret_cast<const float4*>(&As[kk*192 + ty*12]);
      const float4 A1 = *reinterpret_cast<const float4*>(&As[kk*192 + ty*12 + 4]);
      const float4 B0 = *reinterpret_cast<const float4*>(&Bs[kk*192 + tx*12]);
      const float4 B1 = *reinterpret_cast<const float4*>(&Bs[kk*192 + tx*12 + 4]);
      const float a[8] = {A0.x,A0.y,A0.z,A0.w,A1.x,A1.y,A1.z,A1.w};
      const float b[8] = {B0.x,B0.y,B0.z,B0.w,B1.x,B1.y,B1.z,B1.w};
#pragma unroll
      for (int i = 0; i < 8; ++i)
#pragma unroll
        for (int j = 0; j < 8; ++j)
          acc[i][j] += a[i] * b[j];
    }
  }

  const int n0 = col0 + (tx << 3);
  const float4 pb0 = *reinterpret_cast<const float4*>(PB + n0);
  const float4 pb1 = *reinterpret_cast<const float4*>(PB + n0 + 4);
#pragma unroll
  for (int i = 0; i < 8; ++i) {
    const size_t m = row0 + (ty << 3) + i;
    float4 r0, r1;
    r0.x = acc[i][0] + pb0.x; r0.y = acc[i][1] + pb0.y;
    r0.z = acc[i][2] + pb0.z; r0.w = acc[i][3] + pb0.w;
    r1.x = acc[i][4] + pb1.x; r1.y = acc[i][5] + pb1.y;
    r1.z = acc[i][6] + pb1.z; r1.w = acc[i][7] + pb1.w;
    *reinterpret_cast<float4*>(OUT + m*1024 + n0)     = r0;
    *reinterpret_cast<float4*>(OUT + m*1024 + n0 + 4) = r1;
  }
}

// ---------------------------------------------------------------------------
extern "C" void kernel_launch(void* const* d_in, const int* in_sizes, int n_in,
                              void* d_out, int out_size, void* d_ws, size_t ws_size,
                              hipStream_t stream) {
  const float* X    = (const float*)d_in[0];
  const float* Wqkv = (const float*)d_in[1];
  const float* Wp   = (const float*)d_in[2];
  const float* Pb   = (const float*)d_in[3];
  const float* Ct   = (const float*)d_in[4];
  const float* St   = (const float*)d_in[5];
  float* OUT = (float*)d_out;

  // ws layout: q,k,v bf16 (8 MB each) + attn fp32 (16 MB) = 40 MB
  unsigned short* qb = (unsigned short*)d_ws;
  unsigned short* kb = qb + (size_t)4194304;
  unsigned short* vb = kb + (size_t)4194304;
  float* ab = (float*)(vb + (size_t)4194304);

  dim3 g1(32, 24);
  k_qkv_rope<<<g1, 256, 0, stream>>>(X, Wqkv, Ct, St, qb, kb, vb);
  k_attn<<<dim3(1024), 256, 0, stream>>>(qb, kb, vb, ab);
  dim3 g2(32, 8);
  k_proj<<<g2, 256, 0, stream>>>(ab, Wp, Pb, OUT);
}

// Round 4
// 302.200 us; speedup vs baseline: 2.1281x; 2.1281x over previous
//
#include <hip/hip_runtime.h>

// B=2, L=2048, C=1024, H=16, D=64.
// [k_convert]   fp32 -> bf16: Xb (linear), Wb (q/k rows permuted so each head's
//               cols are [even-d | odd-d]), Wpb (linear).
// [k_gemm_qkv]  bf16 MFMA GEMM (M=4096,N=3072,K=1024), m97-style 128x128 tile,
//               BK=32, global_load_lds staging; epilogue: in-lane RoPE (pairs
//               are frags n and n+2 thanks to the W row permutation) + q-scale,
//               scatter bf16 q/k (permuted-d layout) / v into [b][h][l][64].
// [k_attn]      flash attention (unchanged from passing round-3 version except
//               bf16 output). QK^T invariant under the shared d-permutation.
// [k_gemm_proj] bf16 MFMA GEMM (M=4096,N=1024,K=1024) + bias, fp32 out.

typedef __attribute__((ext_vector_type(8))) short s8v;   // 8 x bf16
typedef __attribute__((ext_vector_type(4))) float f4v;   // 4 x f32

__device__ __forceinline__ unsigned short f2bf(float f) {
  unsigned int u = __float_as_uint(f);
  u += 0x7FFFu + ((u >> 16) & 1u);   // RNE
  return (unsigned short)(u >> 16);
}

__device__ __forceinline__ void gl16(const unsigned short* g, unsigned short* l) {
  __builtin_amdgcn_global_load_lds((const __attribute__((address_space(1))) void*)g,
                                   (__attribute__((address_space(3))) void*)l,
                                   16, 0, 0);
}

__device__ __forceinline__ s8v pack8(const float* p) {
  const float4 a = *reinterpret_cast<const float4*>(p);
  const float4 b = *reinterpret_cast<const float4*>(p + 4);
  s8v r;
  r[0]=(short)f2bf(a.x); r[1]=(short)f2bf(a.y); r[2]=(short)f2bf(a.z); r[3]=(short)f2bf(a.w);
  r[4]=(short)f2bf(b.x); r[5]=(short)f2bf(b.y); r[6]=(short)f2bf(b.z); r[7]=(short)f2bf(b.w);
  return r;
}

// ---------------------------------------------------------------------------
// Convert: blocks [0,2048) X (4M), [2048,3584) W (3M, q/k rows permuted),
//          [3584,4096) Wp (1M). 8 floats per thread.
// ---------------------------------------------------------------------------
__global__ __launch_bounds__(256)
void k_convert(const float* __restrict__ X, const float* __restrict__ W,
               const float* __restrict__ Wp,
               unsigned short* __restrict__ Xb, unsigned short* __restrict__ Wb,
               unsigned short* __restrict__ Wpb)
{
  const int bid = blockIdx.x, tid = threadIdx.x;
  if (bid < 2048) {
    const size_t e = (size_t)bid * 2048 + (size_t)tid * 8;
    *reinterpret_cast<s8v*>(Xb + e) = pack8(X + e);
  } else if (bid < 3584) {
    const size_t e = (size_t)(bid - 2048) * 2048 + (size_t)tid * 8;
    const int p = (int)(e >> 10);          // dst row
    const int col = (int)(e & 1023);
    int n;                                  // src row
    if (p < 2048) {                         // q/k: de-interleave head dims
      const int t = p >> 10;
      const int hh = (p & 1023) >> 6;
      const int c = p & 63;
      const int d = (c < 32) ? (c << 1) : (((c - 32) << 1) | 1);
      n = (t << 10) + (hh << 6) + d;
    } else {
      n = p;                                // v: identity
    }
    *reinterpret_cast<s8v*>(Wb + e) = pack8(W + (size_t)n * 1024 + col);
  } else {
    const size_t e = (size_t)(bid - 3584) * 2048 + (size_t)tid * 8;
    *reinterpret_cast<s8v*>(Wpb + e) = pack8(Wp + e);
  }
}

// ---------------------------------------------------------------------------
// GEMM1 (MFMA): qkv = Xb @ Wb^T, fused RoPE/scale epilogue, scatter bf16.
// 128x128 tile, 4 waves (2x2), 4x4 16x16x32 frags/wave, BK=32,
// global_load_lds staging into linear [128][32] bf16 LDS (conflict-free).
// ---------------------------------------------------------------------------
__global__ __launch_bounds__(256)
void k_gemm_qkv(const unsigned short* __restrict__ Ab,   // [4096][1024]
                const unsigned short* __restrict__ Bb,   // [3072][1024] permuted
                const float* __restrict__ Ct, const float* __restrict__ St,
                unsigned short* __restrict__ qb, unsigned short* __restrict__ kb,
                unsigned short* __restrict__ vb)
{
  __shared__ __align__(16) unsigned short Asm[128 * 32];
  __shared__ __align__(16) unsigned short Bsm[128 * 32];

  const int tid  = threadIdx.x;
  const int w    = tid >> 6;
  const int lane = tid & 63;
  const int lr   = lane & 15;
  const int lg   = lane >> 4;
  const int wm   = w >> 1, wn = w & 1;

  const int row0 = blockIdx.x << 7;
  const int col0 = blockIdx.y << 7;

  // staging: wave w covers tile rows [w*32, w*32+32), 16 rows per call
  const int srow = (w << 5) + (lane >> 2);
  const int scol = (lane & 3) << 3;
  const unsigned short* Ag = Ab + (size_t)(row0 + srow) * 1024 + scol;
  const unsigned short* Bg = Bb + (size_t)(col0 + srow) * 1024 + scol;
  unsigned short* Al0 = &Asm[(w << 5) * 32];
  unsigned short* Al1 = Al0 + 512;
  unsigned short* Bl0 = &Bsm[(w << 5) * 32];
  unsigned short* Bl1 = Bl0 + 512;

  f4v acc[4][4];
#pragma unroll
  for (int m = 0; m < 4; ++m)
#pragma unroll
    for (int n = 0; n < 4; ++n) acc[m][n] = (f4v){0.f, 0.f, 0.f, 0.f};

  for (int k0 = 0; k0 < 1024; k0 += 32) {
    gl16(Ag + k0, Al0);
    gl16(Ag + k0 + 16 * 1024, Al1);
    gl16(Bg + k0, Bl0);
    gl16(Bg + k0 + 16 * 1024, Bl1);
    __syncthreads();                 // vmcnt drained before barrier

    s8v af[4], bfr[4];
#pragma unroll
    for (int m = 0; m < 4; ++m)
      af[m] = *reinterpret_cast<const s8v*>(&Asm[(wm * 64 + m * 16 + lr) * 32 + lg * 8]);
#pragma unroll
    for (int n = 0; n < 4; ++n)
      bfr[n] = *reinterpret_cast<const s8v*>(&Bsm[(wn * 64 + n * 16 + lr) * 32 + lg * 8]);
#pragma unroll
    for (int m = 0; m < 4; ++m)
#pragma unroll
      for (int n = 0; n < 4; ++n)
        acc[m][n] = __builtin_amdgcn_mfma_f32_16x16x32_bf16(af[m], bfr[n], acc[m][n], 0, 0, 0);
    __syncthreads();                 // readers done before next stage
  }

  // Epilogue. Wave's 64 cols = exactly one head (permuted: [even-d | odd-d]).
  const int colbase = col0 + wn * 64;
  const int t  = colbase >> 10;
  const int h  = (colbase & 1023) >> 6;
  unsigned short* dst = (t == 0) ? qb : (t == 1) ? kb : vb;
  const float sc = (t == 0) ? 0.125f : 1.0f;

#pragma unroll
  for (int m = 0; m < 4; ++m) {
#pragma unroll
    for (int j = 0; j < 4; ++j) {
      const int token = row0 + wm * 64 + m * 16 + lg * 4 + j;
      const int bI = token >> 11;
      const int lI = token & 2047;
      unsigned short* rowp = dst + (((size_t)bI * 16 + h) * 2048 + lI) * 64;
      if (t == 2) {
#pragma unroll
        for (int n = 0; n < 4; ++n) rowp[n * 16 + lr] = f2bf(acc[m][n][j]);
      } else {
#pragma unroll
        for (int pn = 0; pn < 2; ++pn) {
          const int d2 = pn * 16 + lr;
          const float c = Ct[lI * 32 + d2];
          const float s = St[lI * 32 + d2];
          const float e = acc[m][pn][j];
          const float o = acc[m][pn + 2][j];
          rowp[d2]      = f2bf((e * c - o * s) * sc);
          rowp[32 + d2] = f2bf((e * s + o * c) * sc);
        }
      }
    }
  }
}

// ---------------------------------------------------------------------------
// Flash attention (unchanged math from passing round; output now bf16).
// q/k are in permuted-d layout — QK^T is invariant; V/O in natural order.
// ---------------------------------------------------------------------------
__global__ __launch_bounds__(256)
void k_attn(const unsigned short* __restrict__ qb,
            const unsigned short* __restrict__ kb,
            const unsigned short* __restrict__ vb,
            unsigned short* __restrict__ ab)
{
  __shared__ unsigned short Ps[4][16][72];
  __shared__ unsigned short Vt[64][72];

  const int tid  = threadIdx.x;
  const int w    = tid >> 6;
  const int lane = tid & 63;
  const int lr   = lane & 15;
  const int lg   = lane >> 4;

  const int bx = blockIdx.x;
  const int qt = bx & 31;
  const int h  = (bx >> 5) & 15;
  const int b  = bx >> 9;

  const size_t bh = ((size_t)b * 16 + h) * 2048;
  const unsigned short* Qp = qb + (bh + (size_t)qt * 64 + w * 16) * 64;
  const unsigned short* Kp = kb + bh * 64;
  const unsigned short* Vp = vb + bh * 64;

  const s8v qa0 = *reinterpret_cast<const s8v*>(Qp + lr * 64 + 0 + lg * 8);
  const s8v qa1 = *reinterpret_cast<const s8v*>(Qp + lr * 64 + 32 + lg * 8);

  f4v o[4];
#pragma unroll
  for (int i = 0; i < 4; ++i) o[i] = (f4v){0.f, 0.f, 0.f, 0.f};
  float mrow[4] = {-1e30f, -1e30f, -1e30f, -1e30f};
  float lrow[4] = {0.f, 0.f, 0.f, 0.f};

  const int vc = tid >> 2;
  const int vd = (tid & 3) << 4;

  for (int kt = 0; kt < 32; ++kt) {
    const unsigned short* Kt = Kp + (size_t)kt * 64 * 64;
    const unsigned short* Vs = Vp + (size_t)kt * 64 * 64;

    s8v kf[4][2];
#pragma unroll
    for (int ct = 0; ct < 4; ++ct) {
      kf[ct][0] = *reinterpret_cast<const s8v*>(Kt + (ct * 16 + lr) * 64 + 0 + lg * 8);
      kf[ct][1] = *reinterpret_cast<const s8v*>(Kt + (ct * 16 + lr) * 64 + 32 + lg * 8);
    }
    const s8v v0 = *reinterpret_cast<const s8v*>(Vs + vc * 64 + vd);
    const s8v v1 = *reinterpret_cast<const s8v*>(Vs + vc * 64 + vd + 8);

    __syncthreads();
#pragma unroll
    for (int j = 0; j < 8; ++j) {
      Vt[vd + j][vc]     = (unsigned short)v0[j];
      Vt[vd + 8 + j][vc] = (unsigned short)v1[j];
    }

    f4v s[4];
#pragma unroll
    for (int ct = 0; ct < 4; ++ct) {
      f4v z = (f4v){0.f, 0.f, 0.f, 0.f};
      z = __builtin_amdgcn_mfma_f32_16x16x32_bf16(qa0, kf[ct][0], z, 0, 0, 0);
      z = __builtin_amdgcn_mfma_f32_16x16x32_bf16(qa1, kf[ct][1], z, 0, 0, 0);
      s[ct] = z;
    }

    float pexp[4][4];
#pragma unroll
    for (int r = 0; r < 4; ++r) {
      float mx = fmaxf(fmaxf(s[0][r], s[1][r]), fmaxf(s[2][r], s[3][r]));
#pragma unroll
      for (int mk = 1; mk <= 8; mk <<= 1) mx = fmaxf(mx, __shfl_xor(mx, mk));
      const float mnew = fmaxf(mrow[r], mx);
      const float corr = __expf(mrow[r] - mnew);
      mrow[r] = mnew;
      float rs = 0.f;
#pragma unroll
      for (int ct = 0; ct < 4; ++ct) {
        const float p = __expf(s[ct][r] - mnew);
        pexp[ct][r] = p;
        rs += p;
      }
#pragma unroll
      for (int mk = 1; mk <= 8; mk <<= 1) rs += __shfl_xor(rs, mk);
      lrow[r] = lrow[r] * corr + rs;
      o[0][r] *= corr; o[1][r] *= corr; o[2][r] *= corr; o[3][r] *= corr;
      const int rr = lg * 4 + r;
#pragma unroll
      for (int ct = 0; ct < 4; ++ct)
        Ps[w][rr][ct * 16 + lr] = f2bf(pexp[ct][r]);
    }
    __syncthreads();

    const s8v pa0 = *reinterpret_cast<const s8v*>(&Ps[w][lr][0 + lg * 8]);
    const s8v pa1 = *reinterpret_cast<const s8v*>(&Ps[w][lr][32 + lg * 8]);
#pragma unroll
    for (int dt = 0; dt < 4; ++dt) {
      const s8v vb0 = *reinterpret_cast<const s8v*>(&Vt[dt * 16 + lr][0 + lg * 8]);
      const s8v vb1 = *reinterpret_cast<const s8v*>(&Vt[dt * 16 + lr][32 + lg * 8]);
      o[dt] = __builtin_amdgcn_mfma_f32_16x16x32_bf16(pa0, vb0, o[dt], 0, 0, 0);
      o[dt] = __builtin_amdgcn_mfma_f32_16x16x32_bf16(pa1, vb1, o[dt], 0, 0, 0);
    }
  }

  const int lbase = qt * 64 + w * 16 + lg * 4;
  unsigned short* obase = ab + (size_t)b * 2048 * 1024 + (size_t)h * 64;
#pragma unroll
  for (int r = 0; r < 4; ++r) {
    const float inv = 1.0f / lrow[r];
    unsigned short* orow = obase + (size_t)(lbase + r) * 1024;
    orow[0 + lr]  = f2bf(o[0][r] * inv);
    orow[16 + lr] = f2bf(o[1][r] * inv);
    orow[32 + lr] = f2bf(o[2][r] * inv);
    orow[48 + lr] = f2bf(o[3][r] * inv);
  }
}

// ---------------------------------------------------------------------------
// GEMM2 (MFMA): out = attn @ proj_w^T + bias, fp32 out.
// ---------------------------------------------------------------------------
__global__ __launch_bounds__(256)
void k_gemm_proj(const unsigned short* __restrict__ Ab,   // [4096][1024] bf16
                 const unsigned short* __restrict__ Bb,   // [1024][1024] bf16
                 const float* __restrict__ PB, float* __restrict__ OUT)
{
  __shared__ __align__(16) unsigned short Asm[128 * 32];
  __shared__ __align__(16) unsigned short Bsm[128 * 32];

  const int tid  = threadIdx.x;
  const int w    = tid >> 6;
  const int lane = tid & 63;
  const int lr   = lane & 15;
  const int lg   = lane >> 4;
  const int wm   = w >> 1, wn = w & 1;

  const int row0 = blockIdx.x << 7;
  const int col0 = blockIdx.y << 7;

  const int srow = (w << 5) + (lane >> 2);
  const int scol = (lane & 3) << 3;
  const unsigned short* Ag = Ab + (size_t)(row0 + srow) * 1024 + scol;
  const unsigned short* Bg = Bb + (size_t)(col0 + srow) * 1024 + scol;
  unsigned short* Al0 = &Asm[(w << 5) * 32];
  unsigned short* Al1 = Al0 + 512;
  unsigned short* Bl0 = &Bsm[(w << 5) * 32];
  unsigned short* Bl1 = Bl0 + 512;

  f4v acc[4][4];
#pragma unroll
  for (int m = 0; m < 4; ++m)
#pragma unroll
    for (int n = 0; n < 4; ++n) acc[m][n] = (f4v){0.f, 0.f, 0.f, 0.f};

  for (int k0 = 0; k0 < 1024; k0 += 32) {
    gl16(Ag + k0, Al0);
    gl16(Ag + k0 + 16 * 1024, Al1);
    gl16(Bg + k0, Bl0);
    gl16(Bg + k0 + 16 * 1024, Bl1);
    __syncthreads();

    s8v af[4], bfr[4];
#pragma unroll
    for (int m = 0; m < 4; ++m)
      af[m] = *reinterpret_cast<const s8v*>(&Asm[(wm * 64 + m * 16 + lr) * 32 + lg * 8]);
#pragma unroll
    for (int n = 0; n < 4; ++n)
      bfr[n] = *reinterpret_cast<const s8v*>(&Bsm[(wn * 64 + n * 16 + lr) * 32 + lg * 8]);
#pragma unroll
    for (int m = 0; m < 4; ++m)
#pragma unroll
      for (int n = 0; n < 4; ++n)
        acc[m][n] = __builtin_amdgcn_mfma_f32_16x16x32_bf16(af[m], bfr[n], acc[m][n], 0, 0, 0);
    __syncthreads();
  }

  float bias[4];
#pragma unroll
  for (int n = 0; n < 4; ++n) bias[n] = PB[col0 + wn * 64 + n * 16 + lr];

#pragma unroll
  for (int m = 0; m < 4; ++m) {
#pragma unroll
    for (int j = 0; j < 4; ++j) {
      const size_t token = row0 + wm * 64 + m * 16 + lg * 4 + j;
      float* orow = OUT + token * 1024 + col0 + wn * 64 + lr;
#pragma unroll
      for (int n = 0; n < 4; ++n) orow[n * 16] = acc[m][n][j] + bias[n];
    }
  }
}

// ---------------------------------------------------------------------------
extern "C" void kernel_launch(void* const* d_in, const int* in_sizes, int n_in,
                              void* d_out, int out_size, void* d_ws, size_t ws_size,
                              hipStream_t stream) {
  const float* X    = (const float*)d_in[0];
  const float* Wqkv = (const float*)d_in[1];
  const float* Wp   = (const float*)d_in[2];
  const float* Pb   = (const float*)d_in[3];
  const float* Ct   = (const float*)d_in[4];
  const float* St   = (const float*)d_in[5];
  float* OUT = (float*)d_out;

  // ws: Xb 8MB | Wb 6MB | Wpb 2MB | qb 8MB | kb 8MB | vb 8MB | ab 8MB = 48MB
  unsigned short* Xb  = (unsigned short*)d_ws;
  unsigned short* Wb  = Xb + (size_t)4194304;
  unsigned short* Wpb = Wb + (size_t)3145728;
  unsigned short* qb  = Wpb + (size_t)1048576;
  unsigned short* kb  = qb + (size_t)4194304;
  unsigned short* vb  = kb + (size_t)4194304;
  unsigned short* ab  = vb + (size_t)4194304;

  k_convert<<<dim3(4096), 256, 0, stream>>>(X, Wqkv, Wp, Xb, Wb, Wpb);
  k_gemm_qkv<<<dim3(32, 24), 256, 0, stream>>>(Xb, Wb, Ct, St, qb, kb, vb);
  k_attn<<<dim3(1024), 256, 0, stream>>>(qb, kb, vb, ab);
  k_gemm_proj<<<dim3(32, 8), 256, 0, stream>>>(ab, Wpb, Pb, OUT);
}